// Round 9
// baseline (1030.443 us; speedup 1.0000x reference)
//
#include <hip/hip_runtime.h>
#include <hip/hip_bf16.h>
#include <math.h>

// Problem dims (fixed by reference)
#define BN 1536          // B*N = 2*768
#define NN 768
#define SCALE 0.17677669529663687f  // 1/sqrt(32)
#define NROWS (BN * NN)  // total edge rows = 1179648

// k_bias geometry
#define BIAS_BLOCKS 2048
#define BIAS_WAVES  (BIAS_BLOCKS * 4)            // 8192
#define BIAS_RPW    (NROWS / BIAS_WAVES)         // 144 rows per wave
#define BIAS_NT     (BIAS_RPW / 4)               // 36 quads (multiple of 3)

// ---- DPP reduction helpers (VALU pipe; no LDS traffic) ---------------------
__device__ __forceinline__ float dpp_add16(float x) {
    int t;
    t = __builtin_amdgcn_update_dpp(0, __float_as_int(x), 0x128, 0xF, 0xF, true); // row_ror:8
    x += __int_as_float(t);
    t = __builtin_amdgcn_update_dpp(0, __float_as_int(x), 0x124, 0xF, 0xF, true); // row_ror:4
    x += __int_as_float(t);
    t = __builtin_amdgcn_update_dpp(0, __float_as_int(x), 0x122, 0xF, 0xF, true); // row_ror:2
    x += __int_as_float(t);
    t = __builtin_amdgcn_update_dpp(0, __float_as_int(x), 0x121, 0xF, 0xF, true); // row_ror:1
    x += __int_as_float(t);
    return x;
}
// 8-lane-group sum, pure DPP: xor1 (quad_perm), xor2 (quad_perm), cross-quad
// via row_half_mirror (valid after xor1+xor2 make quads uniform).
__device__ __forceinline__ float dpp_add8(float x) {
    int t;
    t = __builtin_amdgcn_update_dpp(0, __float_as_int(x), 0xB1, 0xF, 0xF, true);
    x += __int_as_float(t);
    t = __builtin_amdgcn_update_dpp(0, __float_as_int(x), 0x4E, 0xF, 0xF, true);
    x += __int_as_float(t);
    t = __builtin_amdgcn_update_dpp(0, __float_as_int(x), 0x141, 0xF, 0xF, true);
    x += __int_as_float(t);
    return x;
}

// ---------------------------------------------------------------------------
// K1: x = LN(node); q = SCALE*(x@Wq); k = x@Wk; v = x@Wv; g = sigmoid(x@Wg+bg)
// ---------------------------------------------------------------------------
__global__ __launch_bounds__(256) void k_lnproj(
    const float* __restrict__ node, const float* __restrict__ lnw,
    const float* __restrict__ lnb, const float* __restrict__ Wq,
    const float* __restrict__ Wk, const float* __restrict__ Wv,
    const float* __restrict__ Wg, const float* __restrict__ bg,
    float* __restrict__ q, float* __restrict__ k,
    float* __restrict__ v, float* __restrict__ g)
{
    __shared__ float xs[8][256];
    const int tid = threadIdx.x;
    const int wave = tid >> 6, lane = tid & 63;
    const int row0 = blockIdx.x * 8;

#pragma unroll
    for (int rr = 0; rr < 2; ++rr) {
        const int r = wave * 2 + rr;
        float4 xv = ((const float4*)node)[(size_t)(row0 + r) * 64 + lane];
        float s1 = xv.x + xv.y + xv.z + xv.w;
        float s2 = fmaf(xv.x, xv.x, fmaf(xv.y, xv.y, fmaf(xv.z, xv.z, xv.w * xv.w)));
#pragma unroll
        for (int off = 32; off > 0; off >>= 1) {
            s1 += __shfl_xor(s1, off);
            s2 += __shfl_xor(s2, off);
        }
        const float mu = s1 * (1.f / 256.f);
        const float rstd = rsqrtf(s2 * (1.f / 256.f) - mu * mu + 1e-5f);
        float4 w4 = ((const float4*)lnw)[lane];
        float4 b4 = ((const float4*)lnb)[lane];
        xs[r][lane * 4 + 0] = (xv.x - mu) * rstd * w4.x + b4.x;
        xs[r][lane * 4 + 1] = (xv.y - mu) * rstd * w4.y + b4.y;
        xs[r][lane * 4 + 2] = (xv.z - mu) * rstd * w4.z + b4.z;
        xs[r][lane * 4 + 3] = (xv.w - mu) * rstd * w4.w + b4.w;
    }
    __syncthreads();

    float aq[8] = {}, ak[8] = {}, av[8] = {}, ag[8] = {};
    for (int e4 = 0; e4 < 64; ++e4) {
        const int e = e4 * 4;
        float wq_[4], wk_[4], wv_[4], wg_[4];
#pragma unroll
        for (int t = 0; t < 4; ++t) {
            wq_[t] = Wq[(e + t) * 256 + tid];
            wk_[t] = Wk[(e + t) * 256 + tid];
            wv_[t] = Wv[(e + t) * 256 + tid];
            wg_[t] = Wg[(e + t) * 256 + tid];
        }
#pragma unroll
        for (int r = 0; r < 8; ++r) {
            float4 xr = *(const float4*)&xs[r][e];
            aq[r] = fmaf(xr.x, wq_[0], fmaf(xr.y, wq_[1], fmaf(xr.z, wq_[2], fmaf(xr.w, wq_[3], aq[r]))));
            ak[r] = fmaf(xr.x, wk_[0], fmaf(xr.y, wk_[1], fmaf(xr.z, wk_[2], fmaf(xr.w, wk_[3], ak[r]))));
            av[r] = fmaf(xr.x, wv_[0], fmaf(xr.y, wv_[1], fmaf(xr.z, wv_[2], fmaf(xr.w, wv_[3], av[r]))));
            ag[r] = fmaf(xr.x, wg_[0], fmaf(xr.y, wg_[1], fmaf(xr.z, wg_[2], fmaf(xr.w, wg_[3], ag[r]))));
        }
    }
    const float bgv = bg[tid];
#pragma unroll
    for (int r = 0; r < 8; ++r) {
        const size_t o = (size_t)(row0 + r) * 256 + tid;
        q[o] = aq[r] * SCALE;
        k[o] = ak[r];
        v[o] = av[r];
        g[o] = 1.f / (1.f + __expf(-(ag[r] + bgv)));
    }
}

// ---------------------------------------------------------------------------
// K2a v6: bias[r][h] = LN(edge_row r) @ Wb — zero-LDS, DPP-reduce.
// FIX vs v4/v5: no lambda, no function taking array pointers. All arrays are
// constant-indexed only (SROA-promotable); runtime selection is an unrolled
// cndmask chain. Theory: prior versions' address-taken arrays were placed in
// LDS by PromoteAlloca (observed: LDS_Block_Size=16384 with no __shared__,
// 14M LDS bank conflicts) -> whole kernel serialized on the LDS pipe.
// 2048 blocks x 4 waves; wave owns 144 rows; 4 rows/iter; 3-buf prefetch.
// ---------------------------------------------------------------------------
#define BIAS_BODY(CUR0, CUR1, ITROW)                                          \
    {                                                                         \
        float s1 = ((CUR0.x + CUR0.y) + (CUR0.z + CUR0.w)) +                  \
                   ((CUR1.x + CUR1.y) + (CUR1.z + CUR1.w));                   \
        float s2 = fmaf(CUR0.x, CUR0.x, fmaf(CUR0.y, CUR0.y,                  \
                   fmaf(CUR0.z, CUR0.z, CUR0.w * CUR0.w)));                   \
        s2 = fmaf(CUR1.x, CUR1.x, fmaf(CUR1.y, CUR1.y,                        \
             fmaf(CUR1.z, CUR1.z, fmaf(CUR1.w, CUR1.w, s2))));                \
        float d[8];                                                           \
        _Pragma("unroll")                                                     \
        for (int hh = 0; hh < 8; ++hh) {                                      \
            float a = CUR0.x * wbf[0][hh];                                    \
            a = fmaf(CUR0.y, wbf[1][hh], a);                                  \
            a = fmaf(CUR0.z, wbf[2][hh], a);                                  \
            a = fmaf(CUR0.w, wbf[3][hh], a);                                  \
            a = fmaf(CUR1.x, wbf[4][hh], a);                                  \
            a = fmaf(CUR1.y, wbf[5][hh], a);                                  \
            a = fmaf(CUR1.z, wbf[6][hh], a);                                  \
            a = fmaf(CUR1.w, wbf[7][hh], a);                                  \
            d[hh] = a;                                                        \
        }                                                                     \
        s1 = dpp_add16(s1);                                                   \
        s2 = dpp_add16(s2);                                                   \
        _Pragma("unroll")                                                     \
        for (int hh = 0; hh < 8; ++hh) d[hh] = dpp_add16(d[hh]);              \
        const float mu = s1 * (1.f / 128.f);                                  \
        const float rstd = rsqrtf(s2 * (1.f / 128.f) - mu * mu + 1e-5f);      \
        float dh = d[0];                                                      \
        _Pragma("unroll")                                                     \
        for (int t = 1; t < 8; ++t) dh = (gl == t) ? d[t] : dh;               \
        if (gl < 8)                                                           \
            bias[(size_t)(row0 + (ITROW)) * 8 + gl] =                         \
                rstd * (dh - mu * c1l) + c0l;                                 \
    }

__global__ __launch_bounds__(256, 3) void k_bias(
    const float* __restrict__ edge, const float* __restrict__ lnw,
    const float* __restrict__ lnb, const float* __restrict__ Wb,
    float* __restrict__ bias, int reps)
{
    const int tid = threadIdx.x;
    const int wv = tid >> 6, lane = tid & 63;
    const int gl = lane & 15;
    const int rg = lane >> 4;

    // folded weights for this lane's 8 channels (constant-indexed only)
    float wbf[8][8];
    float c1a[8], c0a[8];
#pragma unroll
    for (int hh = 0; hh < 8; ++hh) { c1a[hh] = 0.f; c0a[hh] = 0.f; }
#pragma unroll
    for (int t = 0; t < 8; ++t) {
        const int c = (t < 4) ? (gl * 4 + t) : (64 + gl * 4 + (t - 4));
        const float w = lnw[c], bb = lnb[c];
        const float4 wa = ((const float4*)Wb)[c * 2];
        const float4 wc = ((const float4*)Wb)[c * 2 + 1];
        wbf[t][0] = w * wa.x; wbf[t][1] = w * wa.y;
        wbf[t][2] = w * wa.z; wbf[t][3] = w * wa.w;
        wbf[t][4] = w * wc.x; wbf[t][5] = w * wc.y;
        wbf[t][6] = w * wc.z; wbf[t][7] = w * wc.w;
        c0a[0] = fmaf(bb, wa.x, c0a[0]); c0a[1] = fmaf(bb, wa.y, c0a[1]);
        c0a[2] = fmaf(bb, wa.z, c0a[2]); c0a[3] = fmaf(bb, wa.w, c0a[3]);
        c0a[4] = fmaf(bb, wc.x, c0a[4]); c0a[5] = fmaf(bb, wc.y, c0a[5]);
        c0a[6] = fmaf(bb, wc.z, c0a[6]); c0a[7] = fmaf(bb, wc.w, c0a[7]);
#pragma unroll
        for (int hh = 0; hh < 8; ++hh) c1a[hh] += wbf[t][hh];
    }
#pragma unroll
    for (int hh = 0; hh < 8; ++hh) {
        c1a[hh] = dpp_add16(c1a[hh]);
        c0a[hh] = dpp_add16(c0a[hh]);
    }
    // runtime select WITHOUT address-taking: unrolled cndmask chain
    float c1l = c1a[0], c0l = c0a[0];
#pragma unroll
    for (int t = 1; t < 8; ++t) {
        const bool e = ((gl & 7) == t);
        c1l = e ? c1a[t] : c1l;
        c0l = e ? c0a[t] : c0l;
    }

    const int w = blockIdx.x * 4 + wv;     // 0..8191
    const int row0 = w * BIAS_RPW;         // 144 rows/wave
    const float4* ep = (const float4*)edge;

    for (int rep = 0; rep < reps; ++rep) {
        float4 A0, A1, B0, B1, C0, C1;
        {
            const size_t r = (size_t)(row0 + rg);
            A0 = ep[r * 32 + gl]; A1 = ep[r * 32 + 16 + gl];
        }
        {
            const size_t r = (size_t)(row0 + 4 + rg);
            B0 = ep[r * 32 + gl]; B1 = ep[r * 32 + 16 + gl];
        }

#define BSTEP(IT, CUR0, CUR1, NXT0, NXT1)                                 \
        {                                                                 \
            if ((IT) + 2 < BIAS_NT) {                                     \
                const size_t r = (size_t)(row0 + ((IT) + 2) * 4 + rg);    \
                NXT0 = ep[r * 32 + gl]; NXT1 = ep[r * 32 + 16 + gl];      \
            }                                                             \
            BIAS_BODY(CUR0, CUR1, (IT) * 4 + rg);                         \
        }

        for (int it = 0; it < BIAS_NT; it += 3) {
            BSTEP(it,     A0, A1, C0, C1);
            BSTEP(it + 1, B0, B1, A0, A1);
            BSTEP(it + 2, C0, C1, B0, B1);
        }
#undef BSTEP
    }
}

// ---------------------------------------------------------------------------
// K2b v6: flash attention (unchanged body from R8). One block per (b,i),
// 4 waves x 192 j's; pure-DPP octet reduce; LDS merge at end. reps for
// measurement (surfaces in top-5 with counters).
// ---------------------------------------------------------------------------
__global__ __launch_bounds__(256, 4) void k_attn6(
    const float* __restrict__ bias,
    const float* __restrict__ q, const float* __restrict__ k,
    const float* __restrict__ v, const float* __restrict__ g,
    float* __restrict__ res, int reps)
{
    __shared__ float mg[4][64][6];
    const int tid = threadIdx.x;
    const int wv = tid >> 6, lane = tid & 63;
    const int bi = blockIdx.x;
    const int b = bi / NN;
    const int h = lane >> 3;

    const float4 q4 = ((const float4*)q)[(size_t)bi * 64 + lane];
    const float* brow = bias + (size_t)bi * NN * 8;
    const size_t kb = (size_t)b * NN * 64;
    const int j0 = wv * (NN / 4);     // 0,192,384,576

    for (int rep = 0; rep < reps; ++rep) {
        float m = -3e38f, s = 0.f;
        float4 acc = make_float4(0.f, 0.f, 0.f, 0.f);

        for (int t = 0; t < NN / 16; ++t) {      // 48 iters x 4 j
            const int jb = j0 + t * 4;
            float l[4];
            float4 vc[4];
#pragma unroll
            for (int u = 0; u < 4; ++u) {
                const float4 kc = ((const float4*)k)[kb + (size_t)(jb + u) * 64 + lane];
                vc[u] = ((const float4*)v)[kb + (size_t)(jb + u) * 64 + lane];
                float d = fmaf(q4.x, kc.x, fmaf(q4.y, kc.y,
                          fmaf(q4.z, kc.z, q4.w * kc.w)));
                d = dpp_add8(d);
                l[u] = d + brow[(jb + u) * 8 + h];
            }
            const float lm = fmaxf(fmaxf(l[0], l[1]), fmaxf(l[2], l[3]));
            const float mn = fmaxf(m, lm);
            const float sc = __expf(m - mn);
            float p[4];
#pragma unroll
            for (int u = 0; u < 4; ++u) p[u] = __expf(l[u] - mn);
            s = fmaf(s, sc, (p[0] + p[1]) + (p[2] + p[3]));
            m = mn;
            acc.x = fmaf(p[3], vc[3].x, fmaf(p[2], vc[2].x,
                    fmaf(p[1], vc[1].x, fmaf(p[0], vc[0].x, acc.x * sc))));
            acc.y = fmaf(p[3], vc[3].y, fmaf(p[2], vc[2].y,
                    fmaf(p[1], vc[1].y, fmaf(p[0], vc[0].y, acc.y * sc))));
            acc.z = fmaf(p[3], vc[3].z, fmaf(p[2], vc[2].z,
                    fmaf(p[1], vc[1].z, fmaf(p[0], vc[0].z, acc.z * sc))));
            acc.w = fmaf(p[3], vc[3].w, fmaf(p[2], vc[2].w,
                    fmaf(p[1], vc[1].w, fmaf(p[0], vc[0].w, acc.w * sc))));
        }

        mg[wv][lane][0] = m;
        mg[wv][lane][1] = s;
        mg[wv][lane][2] = acc.x;
        mg[wv][lane][3] = acc.y;
        mg[wv][lane][4] = acc.z;
        mg[wv][lane][5] = acc.w;
        __syncthreads();
        if (wv == 0) {
            float M = mg[0][lane][0];
#pragma unroll
            for (int w2 = 1; w2 < 4; ++w2) M = fmaxf(M, mg[w2][lane][0]);
            float S = 0.f;
            float4 A = make_float4(0.f, 0.f, 0.f, 0.f);
#pragma unroll
            for (int w2 = 0; w2 < 4; ++w2) {
                const float sc2 = __expf(mg[w2][lane][0] - M);
                S = fmaf(mg[w2][lane][1], sc2, S);
                A.x = fmaf(mg[w2][lane][2], sc2, A.x);
                A.y = fmaf(mg[w2][lane][3], sc2, A.y);
                A.z = fmaf(mg[w2][lane][4], sc2, A.z);
                A.w = fmaf(mg[w2][lane][5], sc2, A.w);
            }
            const float4 g4 = ((const float4*)g)[(size_t)bi * 64 + lane];
            const float inv = 1.f / S;
            float4 r;
            r.x = A.x * inv * g4.x;
            r.y = A.y * inv * g4.y;
            r.z = A.z * inv * g4.z;
            r.w = A.w * inv * g4.w;
            ((float4*)res)[(size_t)bi * 64 + lane] = r;
        }
        __syncthreads();
    }
}

// ---------------------------------------------------------------------------
// K3: out = res @ Wo + bo.  8 rows per block.
// ---------------------------------------------------------------------------
__global__ __launch_bounds__(256) void k_outproj(
    const float* __restrict__ res, const float* __restrict__ Wo,
    const float* __restrict__ bo, float* __restrict__ out)
{
    __shared__ float xs[8][256];
    const int tid = threadIdx.x;
    const int row0 = blockIdx.x * 8;

#pragma unroll
    for (int t = tid; t < 512; t += 256)
        ((float4*)&xs[0][0])[t] = ((const float4*)(res + (size_t)row0 * 256))[t];
    __syncthreads();

    float a[8] = {};
    for (int e4 = 0; e4 < 64; ++e4) {
        const int e = e4 * 4;
        float w_[4];
#pragma unroll
        for (int t = 0; t < 4; ++t) w_[t] = Wo[(e + t) * 256 + tid];
#pragma unroll
        for (int r = 0; r < 8; ++r) {
            float4 xr = *(const float4*)&xs[r][e];
            a[r] = fmaf(xr.x, w_[0], fmaf(xr.y, w_[1], fmaf(xr.z, w_[2], fmaf(xr.w, w_[3], a[r]))));
        }
    }
    const float bov = bo[tid];
#pragma unroll
    for (int r = 0; r < 8; ++r)
        out[(size_t)(row0 + r) * 256 + tid] = a[r] + bov;
}

// ---------------------------------------------------------------------------
extern "C" void kernel_launch(void* const* d_in, const int* in_sizes, int n_in,
                              void* d_out, int out_size, void* d_ws, size_t ws_size,
                              hipStream_t stream) {
    const float* node = (const float*)d_in[0];
    const float* edge = (const float*)d_in[1];
    const float* lnnw = (const float*)d_in[2];
    const float* lnnb = (const float*)d_in[3];
    const float* lnew = (const float*)d_in[4];
    const float* lneb = (const float*)d_in[5];
    const float* Wq   = (const float*)d_in[6];
    const float* Wk   = (const float*)d_in[7];
    const float* Wv   = (const float*)d_in[8];
    const float* Wb   = (const float*)d_in[9];
    const float* Wg   = (const float*)d_in[10];
    const float* bg   = (const float*)d_in[11];
    const float* Wo   = (const float*)d_in[12];
    const float* bo   = (const float*)d_in[13];
    float* out = (float*)d_out;

    float* ws = (float*)d_ws;
    const size_t NT = (size_t)BN * 256;
    float* q    = ws;
    float* k    = ws + NT;
    float* v    = ws + 2 * NT;
    float* g    = ws + 3 * NT;
    float* res  = ws + 4 * NT;
    float* bias = ws + 5 * NT;            // 9.44M floats = 37.75 MB

    k_lnproj<<<BN / 8, 256, 0, stream>>>(node, lnnw, lnnb, Wq, Wk, Wv, Wg, bg, q, k, v, g);
    k_bias<<<BIAS_BLOCKS, 256, 0, stream>>>(edge, lnew, lneb, Wb, bias, 4);
    k_attn6<<<BN, 256, 0, stream>>>(bias, q, k, v, g, res, 6);
    k_outproj<<<BN / 8, 256, 0, stream>>>(res, Wo, bo, out);
}

// Round 10
// 474.805 us; speedup vs baseline: 2.1702x; 2.1702x over previous
//
#include <hip/hip_runtime.h>
#include <hip/hip_bf16.h>
#include <math.h>

// Problem dims (fixed by reference)
#define BN 1536          // B*N = 2*768
#define NN 768
#define SCALE 0.17677669529663687f  // 1/sqrt(32)
#define NROWS (BN * NN)  // total edge rows = 1179648

// k_bias geometry
#define BIAS_BLOCKS 2048
#define BIAS_WAVES  (BIAS_BLOCKS * 4)            // 8192
#define BIAS_RPW    (NROWS / BIAS_WAVES)         // 144 rows per wave
#define BIAS_NT     (BIAS_RPW / 4)               // 36 quads (multiple of 3)

// ---- DPP reduction helpers (VALU pipe; no LDS traffic) ---------------------
__device__ __forceinline__ float dpp_add16(float x) {
    int t;
    t = __builtin_amdgcn_update_dpp(0, __float_as_int(x), 0x128, 0xF, 0xF, true); // row_ror:8
    x += __int_as_float(t);
    t = __builtin_amdgcn_update_dpp(0, __float_as_int(x), 0x124, 0xF, 0xF, true); // row_ror:4
    x += __int_as_float(t);
    t = __builtin_amdgcn_update_dpp(0, __float_as_int(x), 0x122, 0xF, 0xF, true); // row_ror:2
    x += __int_as_float(t);
    t = __builtin_amdgcn_update_dpp(0, __float_as_int(x), 0x121, 0xF, 0xF, true); // row_ror:1
    x += __int_as_float(t);
    return x;
}
// 8-lane-group sum / max, pure DPP (verified on HW in R8/R9 via k_attn6):
// quad_perm xor1 (0xB1), quad_perm xor2 (0x4E), row_half_mirror (0x141).
__device__ __forceinline__ float dpp_add8(float x) {
    int t;
    t = __builtin_amdgcn_update_dpp(0, __float_as_int(x), 0xB1, 0xF, 0xF, true);
    x += __int_as_float(t);
    t = __builtin_amdgcn_update_dpp(0, __float_as_int(x), 0x4E, 0xF, 0xF, true);
    x += __int_as_float(t);
    t = __builtin_amdgcn_update_dpp(0, __float_as_int(x), 0x141, 0xF, 0xF, true);
    x += __int_as_float(t);
    return x;
}
__device__ __forceinline__ float dpp_max8(float x) {
    int t;
    t = __builtin_amdgcn_update_dpp(0, __float_as_int(x), 0xB1, 0xF, 0xF, true);
    x = fmaxf(x, __int_as_float(t));
    t = __builtin_amdgcn_update_dpp(0, __float_as_int(x), 0x4E, 0xF, 0xF, true);
    x = fmaxf(x, __int_as_float(t));
    t = __builtin_amdgcn_update_dpp(0, __float_as_int(x), 0x141, 0xF, 0xF, true);
    x = fmaxf(x, __int_as_float(t));
    return x;
}
__device__ __forceinline__ float4 dpp_add8_f4(float4 x) {
    x.x = dpp_add8(x.x); x.y = dpp_add8(x.y);
    x.z = dpp_add8(x.z); x.w = dpp_add8(x.w);
    return x;
}

// ---------------------------------------------------------------------------
// K1: x = LN(node); q = SCALE*(x@Wq); k = x@Wk; v = x@Wv; g = sigmoid(x@Wg+bg)
// ---------------------------------------------------------------------------
__global__ __launch_bounds__(256) void k_lnproj(
    const float* __restrict__ node, const float* __restrict__ lnw,
    const float* __restrict__ lnb, const float* __restrict__ Wq,
    const float* __restrict__ Wk, const float* __restrict__ Wv,
    const float* __restrict__ Wg, const float* __restrict__ bg,
    float* __restrict__ q, float* __restrict__ k,
    float* __restrict__ v, float* __restrict__ g)
{
    __shared__ float xs[8][256];
    const int tid = threadIdx.x;
    const int wave = tid >> 6, lane = tid & 63;
    const int row0 = blockIdx.x * 8;

#pragma unroll
    for (int rr = 0; rr < 2; ++rr) {
        const int r = wave * 2 + rr;
        float4 xv = ((const float4*)node)[(size_t)(row0 + r) * 64 + lane];
        float s1 = xv.x + xv.y + xv.z + xv.w;
        float s2 = fmaf(xv.x, xv.x, fmaf(xv.y, xv.y, fmaf(xv.z, xv.z, xv.w * xv.w)));
#pragma unroll
        for (int off = 32; off > 0; off >>= 1) {
            s1 += __shfl_xor(s1, off);
            s2 += __shfl_xor(s2, off);
        }
        const float mu = s1 * (1.f / 256.f);
        const float rstd = rsqrtf(s2 * (1.f / 256.f) - mu * mu + 1e-5f);
        float4 w4 = ((const float4*)lnw)[lane];
        float4 b4 = ((const float4*)lnb)[lane];
        xs[r][lane * 4 + 0] = (xv.x - mu) * rstd * w4.x + b4.x;
        xs[r][lane * 4 + 1] = (xv.y - mu) * rstd * w4.y + b4.y;
        xs[r][lane * 4 + 2] = (xv.z - mu) * rstd * w4.z + b4.z;
        xs[r][lane * 4 + 3] = (xv.w - mu) * rstd * w4.w + b4.w;
    }
    __syncthreads();

    float aq[8] = {}, ak[8] = {}, av[8] = {}, ag[8] = {};
    for (int e4 = 0; e4 < 64; ++e4) {
        const int e = e4 * 4;
        float wq_[4], wk_[4], wv_[4], wg_[4];
#pragma unroll
        for (int t = 0; t < 4; ++t) {
            wq_[t] = Wq[(e + t) * 256 + tid];
            wk_[t] = Wk[(e + t) * 256 + tid];
            wv_[t] = Wv[(e + t) * 256 + tid];
            wg_[t] = Wg[(e + t) * 256 + tid];
        }
#pragma unroll
        for (int r = 0; r < 8; ++r) {
            float4 xr = *(const float4*)&xs[r][e];
            aq[r] = fmaf(xr.x, wq_[0], fmaf(xr.y, wq_[1], fmaf(xr.z, wq_[2], fmaf(xr.w, wq_[3], aq[r]))));
            ak[r] = fmaf(xr.x, wk_[0], fmaf(xr.y, wk_[1], fmaf(xr.z, wk_[2], fmaf(xr.w, wk_[3], ak[r]))));
            av[r] = fmaf(xr.x, wv_[0], fmaf(xr.y, wv_[1], fmaf(xr.z, wv_[2], fmaf(xr.w, wv_[3], av[r]))));
            ag[r] = fmaf(xr.x, wg_[0], fmaf(xr.y, wg_[1], fmaf(xr.z, wg_[2], fmaf(xr.w, wg_[3], ag[r]))));
        }
    }
    const float bgv = bg[tid];
#pragma unroll
    for (int r = 0; r < 8; ++r) {
        const size_t o = (size_t)(row0 + r) * 256 + tid;
        q[o] = aq[r] * SCALE;
        k[o] = ak[r];
        v[o] = av[r];
        g[o] = 1.f / (1.f + __expf(-(ag[r] + bgv)));
    }
}

// ---------------------------------------------------------------------------
// K2a v6 (unchanged from R9 — measured at the edge-read roofline ~96us/rep).
// Zero-LDS, DPP-reduce, all arrays constant-indexed (no address-taking ->
// no PromoteAlloca-to-LDS).
// ---------------------------------------------------------------------------
#define BIAS_BODY(CUR0, CUR1, ITROW)                                          \
    {                                                                         \
        float s1 = ((CUR0.x + CUR0.y) + (CUR0.z + CUR0.w)) +                  \
                   ((CUR1.x + CUR1.y) + (CUR1.z + CUR1.w));                   \
        float s2 = fmaf(CUR0.x, CUR0.x, fmaf(CUR0.y, CUR0.y,                  \
                   fmaf(CUR0.z, CUR0.z, CUR0.w * CUR0.w)));                   \
        s2 = fmaf(CUR1.x, CUR1.x, fmaf(CUR1.y, CUR1.y,                        \
             fmaf(CUR1.z, CUR1.z, fmaf(CUR1.w, CUR1.w, s2))));                \
        float d[8];                                                           \
        _Pragma("unroll")                                                     \
        for (int hh = 0; hh < 8; ++hh) {                                      \
            float a = CUR0.x * wbf[0][hh];                                    \
            a = fmaf(CUR0.y, wbf[1][hh], a);                                  \
            a = fmaf(CUR0.z, wbf[2][hh], a);                                  \
            a = fmaf(CUR0.w, wbf[3][hh], a);                                  \
            a = fmaf(CUR1.x, wbf[4][hh], a);                                  \
            a = fmaf(CUR1.y, wbf[5][hh], a);                                  \
            a = fmaf(CUR1.z, wbf[6][hh], a);                                  \
            a = fmaf(CUR1.w, wbf[7][hh], a);                                  \
            d[hh] = a;                                                        \
        }                                                                     \
        s1 = dpp_add16(s1);                                                   \
        s2 = dpp_add16(s2);                                                   \
        _Pragma("unroll")                                                     \
        for (int hh = 0; hh < 8; ++hh) d[hh] = dpp_add16(d[hh]);              \
        const float mu = s1 * (1.f / 128.f);                                  \
        const float rstd = rsqrtf(s2 * (1.f / 128.f) - mu * mu + 1e-5f);      \
        float dh = d[0];                                                      \
        _Pragma("unroll")                                                     \
        for (int t = 1; t < 8; ++t) dh = (gl == t) ? d[t] : dh;               \
        if (gl < 8)                                                           \
            bias[(size_t)(row0 + (ITROW)) * 8 + gl] =                         \
                rstd * (dh - mu * c1l) + c0l;                                 \
    }

__global__ __launch_bounds__(256, 3) void k_bias(
    const float* __restrict__ edge, const float* __restrict__ lnw,
    const float* __restrict__ lnb, const float* __restrict__ Wb,
    float* __restrict__ bias, int reps)
{
    const int tid = threadIdx.x;
    const int wv = tid >> 6, lane = tid & 63;
    const int gl = lane & 15;
    const int rg = lane >> 4;

    float wbf[8][8];
    float c1a[8], c0a[8];
#pragma unroll
    for (int hh = 0; hh < 8; ++hh) { c1a[hh] = 0.f; c0a[hh] = 0.f; }
#pragma unroll
    for (int t = 0; t < 8; ++t) {
        const int c = (t < 4) ? (gl * 4 + t) : (64 + gl * 4 + (t - 4));
        const float w = lnw[c], bb = lnb[c];
        const float4 wa = ((const float4*)Wb)[c * 2];
        const float4 wc = ((const float4*)Wb)[c * 2 + 1];
        wbf[t][0] = w * wa.x; wbf[t][1] = w * wa.y;
        wbf[t][2] = w * wa.z; wbf[t][3] = w * wa.w;
        wbf[t][4] = w * wc.x; wbf[t][5] = w * wc.y;
        wbf[t][6] = w * wc.z; wbf[t][7] = w * wc.w;
        c0a[0] = fmaf(bb, wa.x, c0a[0]); c0a[1] = fmaf(bb, wa.y, c0a[1]);
        c0a[2] = fmaf(bb, wa.z, c0a[2]); c0a[3] = fmaf(bb, wa.w, c0a[3]);
        c0a[4] = fmaf(bb, wc.x, c0a[4]); c0a[5] = fmaf(bb, wc.y, c0a[5]);
        c0a[6] = fmaf(bb, wc.z, c0a[6]); c0a[7] = fmaf(bb, wc.w, c0a[7]);
#pragma unroll
        for (int hh = 0; hh < 8; ++hh) c1a[hh] += wbf[t][hh];
    }
#pragma unroll
    for (int hh = 0; hh < 8; ++hh) {
        c1a[hh] = dpp_add16(c1a[hh]);
        c0a[hh] = dpp_add16(c0a[hh]);
    }
    float c1l = c1a[0], c0l = c0a[0];
#pragma unroll
    for (int t = 1; t < 8; ++t) {
        const bool e = ((gl & 7) == t);
        c1l = e ? c1a[t] : c1l;
        c0l = e ? c0a[t] : c0l;
    }

    const int w = blockIdx.x * 4 + wv;     // 0..8191
    const int row0 = w * BIAS_RPW;         // 144 rows/wave
    const float4* ep = (const float4*)edge;

    for (int rep = 0; rep < reps; ++rep) {
        float4 A0, A1, B0, B1, C0, C1;
        {
            const size_t r = (size_t)(row0 + rg);
            A0 = ep[r * 32 + gl]; A1 = ep[r * 32 + 16 + gl];
        }
        {
            const size_t r = (size_t)(row0 + 4 + rg);
            B0 = ep[r * 32 + gl]; B1 = ep[r * 32 + 16 + gl];
        }

#define BSTEP(IT, CUR0, CUR1, NXT0, NXT1)                                 \
        {                                                                 \
            if ((IT) + 2 < BIAS_NT) {                                     \
                const size_t r = (size_t)(row0 + ((IT) + 2) * 4 + rg);    \
                NXT0 = ep[r * 32 + gl]; NXT1 = ep[r * 32 + 16 + gl];      \
            }                                                             \
            BIAS_BODY(CUR0, CUR1, (IT) * 4 + rg);                         \
        }

        for (int it = 0; it < BIAS_NT; it += 3) {
            BSTEP(it,     A0, A1, C0, C1);
            BSTEP(it + 1, B0, B1, A0, A1);
            BSTEP(it + 2, C0, C1, B0, B1);
        }
#undef BSTEP
    }
}

// ---------------------------------------------------------------------------
// K2b v7: lane-local flash attention.
// Block = 4 waves = 2 q-rows (r = wv>>1) x 2 j-halves (jq = wv&1).
// Lane = (h = lane>>3, jj = lane&7): owns head h, j = jq*384 + t*8 + jj,
// holds full 32-dim q[h] and acc[32] in registers. Dot is 32 in-lane fmas —
// ZERO cross-lane ops in the loop; per-lane online softmax with __any-gated
// deferred rescale. Merge: DPP-8 over jj once per wave, then LDS across
// the 2 j-half waves. K/V read once per 2 q-rows (L2 traffic halved).
// grid 768 = 3 blocks/CU exactly; ~150 VGPR (launch_bounds 256,3).
// ---------------------------------------------------------------------------
__global__ __launch_bounds__(256, 3) void k_attn7(
    const float* __restrict__ bias,
    const float* __restrict__ q, const float* __restrict__ k,
    const float* __restrict__ v, const float* __restrict__ g,
    float* __restrict__ res)
{
    __shared__ __align__(16) float lmrg[4][8][40];   // 5.1 KB
    const int tid = threadIdx.x;
    const int wv = tid >> 6, lane = tid & 63;
    const int r = wv >> 1, jq = wv & 1;
    const int h = lane >> 3, jj = lane & 7;
    const int bi = blockIdx.x * 2 + r;
    const int b = bi / NN;

    // full q[bi, h, 0..31], pre-scaled by 1/sqrt(32)
    const float4* qp = (const float4*)(q + (size_t)bi * 256 + h * 32);
    const float4 q0 = qp[0], q1 = qp[1], q2 = qp[2], q3 = qp[3];
    const float4 q4 = qp[4], q5 = qp[5], q6 = qp[6], q7 = qp[7];

    const float* kbp = k + (size_t)b * NN * 256 + h * 32;
    const float* vbp = v + (size_t)b * NN * 256 + h * 32;
    const float* brow = bias + (size_t)bi * NN * 8;

    float m = -3e38f, s = 0.f;
    float4 a0 = {0,0,0,0}, a1 = {0,0,0,0}, a2 = {0,0,0,0}, a3 = {0,0,0,0};
    float4 a4 = {0,0,0,0}, a5 = {0,0,0,0}, a6 = {0,0,0,0}, a7 = {0,0,0,0};

    for (int t = 0; t < 48; ++t) {
        const int j = jq * 384 + t * 8 + jj;
        const float4* kr = (const float4*)(kbp + (size_t)j * 256);
        const float4* vr = (const float4*)(vbp + (size_t)j * 256);
        const float4 t0 = kr[0], t1 = kr[1], t2 = kr[2], t3 = kr[3];
        const float4 t4 = kr[4], t5 = kr[5], t6 = kr[6], t7 = kr[7];
        const float4 u0 = vr[0], u1 = vr[1], u2 = vr[2], u3 = vr[3];
        const float4 u4 = vr[4], u5 = vr[5], u6 = vr[6], u7 = vr[7];
        const float bj = brow[j * 8 + h];

        float da = t0.x * q0.x;
        da = fmaf(t0.y, q0.y, da); da = fmaf(t0.z, q0.z, da); da = fmaf(t0.w, q0.w, da);
        da = fmaf(t1.x, q1.x, da); da = fmaf(t1.y, q1.y, da);
        da = fmaf(t1.z, q1.z, da); da = fmaf(t1.w, q1.w, da);
        float db = t2.x * q2.x;
        db = fmaf(t2.y, q2.y, db); db = fmaf(t2.z, q2.z, db); db = fmaf(t2.w, q2.w, db);
        db = fmaf(t3.x, q3.x, db); db = fmaf(t3.y, q3.y, db);
        db = fmaf(t3.z, q3.z, db); db = fmaf(t3.w, q3.w, db);
        float dc = t4.x * q4.x;
        dc = fmaf(t4.y, q4.y, dc); dc = fmaf(t4.z, q4.z, dc); dc = fmaf(t4.w, q4.w, dc);
        dc = fmaf(t5.x, q5.x, dc); dc = fmaf(t5.y, q5.y, dc);
        dc = fmaf(t5.z, q5.z, dc); dc = fmaf(t5.w, q5.w, dc);
        float dd = t6.x * q6.x;
        dd = fmaf(t6.y, q6.y, dd); dd = fmaf(t6.z, q6.z, dd); dd = fmaf(t6.w, q6.w, dd);
        dd = fmaf(t7.x, q7.x, dd); dd = fmaf(t7.y, q7.y, dd);
        dd = fmaf(t7.z, q7.z, dd); dd = fmaf(t7.w, q7.w, dd);
        const float l = ((da + db) + (dc + dd)) + bj;

        if (__any(l > m)) {
            const float mn = fmaxf(m, l);
            const float sc = __expf(m - mn);
            const float p = __expf(l - mn);
            s = fmaf(s, sc, p);
            m = mn;
            a0.x = fmaf(p, u0.x, a0.x * sc); a0.y = fmaf(p, u0.y, a0.y * sc);
            a0.z = fmaf(p, u0.z, a0.z * sc); a0.w = fmaf(p, u0.w, a0.w * sc);
            a1.x = fmaf(p, u1.x, a1.x * sc); a1.y = fmaf(p, u1.y, a1.y * sc);
            a1.z = fmaf(p, u1.z, a1.z * sc); a1.w = fmaf(p, u1.w, a1.w * sc);
            a2.x = fmaf(p, u2.x, a2.x * sc); a2.y = fmaf(p, u2.y, a2.y * sc);
            a2.z = fmaf(p, u2.z, a2.z * sc); a2.w = fmaf(p, u2.w, a2.w * sc);
            a3.x = fmaf(p, u3.x, a3.x * sc); a3.y = fmaf(p, u3.y, a3.y * sc);
            a3.z = fmaf(p, u3.z, a3.z * sc); a3.w = fmaf(p, u3.w, a3.w * sc);
            a4.x = fmaf(p, u4.x, a4.x * sc); a4.y = fmaf(p, u4.y, a4.y * sc);
            a4.z = fmaf(p, u4.z, a4.z * sc); a4.w = fmaf(p, u4.w, a4.w * sc);
            a5.x = fmaf(p, u5.x, a5.x * sc); a5.y = fmaf(p, u5.y, a5.y * sc);
            a5.z = fmaf(p, u5.z, a5.z * sc); a5.w = fmaf(p, u5.w, a5.w * sc);
            a6.x = fmaf(p, u6.x, a6.x * sc); a6.y = fmaf(p, u6.y, a6.y * sc);
            a6.z = fmaf(p, u6.z, a6.z * sc); a6.w = fmaf(p, u6.w, a6.w * sc);
            a7.x = fmaf(p, u7.x, a7.x * sc); a7.y = fmaf(p, u7.y, a7.y * sc);
            a7.z = fmaf(p, u7.z, a7.z * sc); a7.w = fmaf(p, u7.w, a7.w * sc);
        } else {
            const float p = __expf(l - m);
            s += p;
            a0.x = fmaf(p, u0.x, a0.x); a0.y = fmaf(p, u0.y, a0.y);
            a0.z = fmaf(p, u0.z, a0.z); a0.w = fmaf(p, u0.w, a0.w);
            a1.x = fmaf(p, u1.x, a1.x); a1.y = fmaf(p, u1.y, a1.y);
            a1.z = fmaf(p, u1.z, a1.z); a1.w = fmaf(p, u1.w, a1.w);
            a2.x = fmaf(p, u2.x, a2.x); a2.y = fmaf(p, u2.y, a2.y);
            a2.z = fmaf(p, u2.z, a2.z); a2.w = fmaf(p, u2.w, a2.w);
            a3.x = fmaf(p, u3.x, a3.x); a3.y = fmaf(p, u3.y, a3.y);
            a3.z = fmaf(p, u3.z, a3.z); a3.w = fmaf(p, u3.w, a3.w);
            a4.x = fmaf(p, u4.x, a4.x); a4.y = fmaf(p, u4.y, a4.y);
            a4.z = fmaf(p, u4.z, a4.z); a4.w = fmaf(p, u4.w, a4.w);
            a5.x = fmaf(p, u5.x, a5.x); a5.y = fmaf(p, u5.y, a5.y);
            a5.z = fmaf(p, u5.z, a5.z); a5.w = fmaf(p, u5.w, a5.w);
            a6.x = fmaf(p, u6.x, a6.x); a6.y = fmaf(p, u6.y, a6.y);
            a6.z = fmaf(p, u6.z, a6.z); a6.w = fmaf(p, u6.w, a6.w);
            a7.x = fmaf(p, u7.x, a7.x); a7.y = fmaf(p, u7.y, a7.y);
            a7.z = fmaf(p, u7.z, a7.z); a7.w = fmaf(p, u7.w, a7.w);
        }
    }

    // ---- intra-wave merge across jj (8 lanes per head) via DPP ----
    const float M = dpp_max8(m);
    const float e = __expf(m - M);
    s *= e;
    a0.x *= e; a0.y *= e; a0.z *= e; a0.w *= e;
    a1.x *= e; a1.y *= e; a1.z *= e; a1.w *= e;
    a2.x *= e; a2.y *= e; a2.z *= e; a2.w *= e;
    a3.x *= e; a3.y *= e; a3.z *= e; a3.w *= e;
    a4.x *= e; a4.y *= e; a4.z *= e; a4.w *= e;
    a5.x *= e; a5.y *= e; a5.z *= e; a5.w *= e;
    a6.x *= e; a6.y *= e; a6.z *= e; a6.w *= e;
    a7.x *= e; a7.y *= e; a7.z *= e; a7.w *= e;
    s = dpp_add8(s);
    a0 = dpp_add8_f4(a0); a1 = dpp_add8_f4(a1);
    a2 = dpp_add8_f4(a2); a3 = dpp_add8_f4(a3);
    a4 = dpp_add8_f4(a4); a5 = dpp_add8_f4(a5);
    a6 = dpp_add8_f4(a6); a7 = dpp_add8_f4(a7);

    if (jj == 0) {
        float* dst = &lmrg[wv][h][0];
        dst[0] = M;
        dst[1] = s;
        float4* d4 = (float4*)(dst + 4);
        d4[0] = a0; d4[1] = a1; d4[2] = a2; d4[3] = a3;
        d4[4] = a4; d4[5] = a5; d4[6] = a6; d4[7] = a7;
    }
    __syncthreads();

    // ---- cross-wave merge (2 j-halves) + gate + store; waves 0,1 ----
    if (wv < 2) {
        const int bi2 = blockIdx.x * 2 + wv;
        const int h2 = lane >> 3, dg = lane & 7;
        const float m0 = lmrg[wv * 2 + 0][h2][0];
        const float s0 = lmrg[wv * 2 + 0][h2][1];
        const float m1 = lmrg[wv * 2 + 1][h2][0];
        const float s1 = lmrg[wv * 2 + 1][h2][1];
        const float M2 = fmaxf(m0, m1);
        const float e0 = __expf(m0 - M2);
        const float e1 = __expf(m1 - M2);
        const float S = s0 * e0 + s1 * e1;
        const float4 x0 = *(const float4*)&lmrg[wv * 2 + 0][h2][4 + dg * 4];
        const float4 x1 = *(const float4*)&lmrg[wv * 2 + 1][h2][4 + dg * 4];
        const float4 g4 = ((const float4*)(g + (size_t)bi2 * 256 + h2 * 32))[dg];
        const float inv = 1.f / S;
        float4 o;
        o.x = (x0.x * e0 + x1.x * e1) * inv * g4.x;
        o.y = (x0.y * e0 + x1.y * e1) * inv * g4.y;
        o.z = (x0.z * e0 + x1.z * e1) * inv * g4.z;
        o.w = (x0.w * e0 + x1.w * e1) * inv * g4.w;
        ((float4*)(res + (size_t)bi2 * 256 + h2 * 32))[dg] = o;
    }
}

// ---------------------------------------------------------------------------
// K3: out = res @ Wo + bo.  8 rows per block.
// ---------------------------------------------------------------------------
__global__ __launch_bounds__(256) void k_outproj(
    const float* __restrict__ res, const float* __restrict__ Wo,
    const float* __restrict__ bo, float* __restrict__ out)
{
    __shared__ float xs[8][256];
    const int tid = threadIdx.x;
    const int row0 = blockIdx.x * 8;

#pragma unroll
    for (int t = tid; t < 512; t += 256)
        ((float4*)&xs[0][0])[t] = ((const float4*)(res + (size_t)row0 * 256))[t];
    __syncthreads();

    float a[8] = {};
    for (int e4 = 0; e4 < 64; ++e4) {
        const int e = e4 * 4;
        float w_[4];
#pragma unroll
        for (int t = 0; t < 4; ++t) w_[t] = Wo[(e + t) * 256 + tid];
#pragma unroll
        for (int r = 0; r < 8; ++r) {
            float4 xr = *(const float4*)&xs[r][e];
            a[r] = fmaf(xr.x, w_[0], fmaf(xr.y, w_[1], fmaf(xr.z, w_[2], fmaf(xr.w, w_[3], a[r]))));
        }
    }
    const float bov = bo[tid];
#pragma unroll
    for (int r = 0; r < 8; ++r)
        out[(size_t)(row0 + r) * 256 + tid] = a[r] + bov;
}

// ---------------------------------------------------------------------------
extern "C" void kernel_launch(void* const* d_in, const int* in_sizes, int n_in,
                              void* d_out, int out_size, void* d_ws, size_t ws_size,
                              hipStream_t stream) {
    const float* node = (const float*)d_in[0];
    const float* edge = (const float*)d_in[1];
    const float* lnnw = (const float*)d_in[2];
    const float* lnnb = (const float*)d_in[3];
    const float* lnew = (const float*)d_in[4];
    const float* lneb = (const float*)d_in[5];
    const float* Wq   = (const float*)d_in[6];
    const float* Wk   = (const float*)d_in[7];
    const float* Wv   = (const float*)d_in[8];
    const float* Wb   = (const float*)d_in[9];
    const float* Wg   = (const float*)d_in[10];
    const float* bg   = (const float*)d_in[11];
    const float* Wo   = (const float*)d_in[12];
    const float* bo   = (const float*)d_in[13];
    float* out = (float*)d_out;

    float* ws = (float*)d_ws;
    const size_t NT = (size_t)BN * 256;
    float* q    = ws;
    float* k    = ws + NT;
    float* v    = ws + 2 * NT;
    float* g    = ws + 3 * NT;
    float* res  = ws + 4 * NT;
    float* bias = ws + 5 * NT;            // 9.44M floats = 37.75 MB

    k_lnproj<<<BN / 8, 256, 0, stream>>>(node, lnnw, lnnb, Wq, Wk, Wv, Wg, bg, q, k, v, g);
    k_bias<<<BIAS_BLOCKS, 256, 0, stream>>>(edge, lnew, lneb, Wb, bias, 1);
    k_attn7<<<BN / 2, 256, 0, stream>>>(bias, q, k, v, g, res);
    k_outproj<<<BN / 8, 256, 0, stream>>>(res, Wo, bo, out);
}

// Round 11
// 329.294 us; speedup vs baseline: 3.1292x; 1.4419x over previous
//
#include <hip/hip_runtime.h>
#include <hip/hip_bf16.h>
#include <math.h>

// Problem dims (fixed by reference)
#define BN 1536          // B*N = 2*768
#define NN 768
#define SCALE 0.17677669529663687f  // 1/sqrt(32)
#define NROWS (BN * NN)  // total edge rows = 1179648

// k_bias geometry
#define BIAS_BLOCKS 2048
#define BIAS_WAVES  (BIAS_BLOCKS * 4)            // 8192
#define BIAS_RPW    (NROWS / BIAS_WAVES)         // 144 rows per wave
#define BIAS_NT     (BIAS_RPW / 4)               // 36 quads (multiple of 3)

// ---- DPP reduction helpers (VALU pipe; no LDS traffic) ---------------------
__device__ __forceinline__ float dpp_add16(float x) {
    int t;
    t = __builtin_amdgcn_update_dpp(0, __float_as_int(x), 0x128, 0xF, 0xF, true); // row_ror:8
    x += __int_as_float(t);
    t = __builtin_amdgcn_update_dpp(0, __float_as_int(x), 0x124, 0xF, 0xF, true); // row_ror:4
    x += __int_as_float(t);
    t = __builtin_amdgcn_update_dpp(0, __float_as_int(x), 0x122, 0xF, 0xF, true); // row_ror:2
    x += __int_as_float(t);
    t = __builtin_amdgcn_update_dpp(0, __float_as_int(x), 0x121, 0xF, 0xF, true); // row_ror:1
    x += __int_as_float(t);
    return x;
}
// 8-lane-group sum, pure DPP (HW-verified via k_attn6 in R8/R9):
// quad_perm xor1 (0xB1), quad_perm xor2 (0x4E), row_half_mirror (0x141).
__device__ __forceinline__ float dpp_add8(float x) {
    int t;
    t = __builtin_amdgcn_update_dpp(0, __float_as_int(x), 0xB1, 0xF, 0xF, true);
    x += __int_as_float(t);
    t = __builtin_amdgcn_update_dpp(0, __float_as_int(x), 0x4E, 0xF, 0xF, true);
    x += __int_as_float(t);
    t = __builtin_amdgcn_update_dpp(0, __float_as_int(x), 0x141, 0xF, 0xF, true);
    x += __int_as_float(t);
    return x;
}

// ---------------------------------------------------------------------------
// K1: x = LN(node); q = SCALE*(x@Wq); k = x@Wk; v = x@Wv; g = sigmoid(x@Wg+bg)
// ---------------------------------------------------------------------------
__global__ __launch_bounds__(256) void k_lnproj(
    const float* __restrict__ node, const float* __restrict__ lnw,
    const float* __restrict__ lnb, const float* __restrict__ Wq,
    const float* __restrict__ Wk, const float* __restrict__ Wv,
    const float* __restrict__ Wg, const float* __restrict__ bg,
    float* __restrict__ q, float* __restrict__ k,
    float* __restrict__ v, float* __restrict__ g)
{
    __shared__ float xs[8][256];
    const int tid = threadIdx.x;
    const int wave = tid >> 6, lane = tid & 63;
    const int row0 = blockIdx.x * 8;

#pragma unroll
    for (int rr = 0; rr < 2; ++rr) {
        const int r = wave * 2 + rr;
        float4 xv = ((const float4*)node)[(size_t)(row0 + r) * 64 + lane];
        float s1 = xv.x + xv.y + xv.z + xv.w;
        float s2 = fmaf(xv.x, xv.x, fmaf(xv.y, xv.y, fmaf(xv.z, xv.z, xv.w * xv.w)));
#pragma unroll
        for (int off = 32; off > 0; off >>= 1) {
            s1 += __shfl_xor(s1, off);
            s2 += __shfl_xor(s2, off);
        }
        const float mu = s1 * (1.f / 256.f);
        const float rstd = rsqrtf(s2 * (1.f / 256.f) - mu * mu + 1e-5f);
        float4 w4 = ((const float4*)lnw)[lane];
        float4 b4 = ((const float4*)lnb)[lane];
        xs[r][lane * 4 + 0] = (xv.x - mu) * rstd * w4.x + b4.x;
        xs[r][lane * 4 + 1] = (xv.y - mu) * rstd * w4.y + b4.y;
        xs[r][lane * 4 + 2] = (xv.z - mu) * rstd * w4.z + b4.z;
        xs[r][lane * 4 + 3] = (xv.w - mu) * rstd * w4.w + b4.w;
    }
    __syncthreads();

    float aq[8] = {}, ak[8] = {}, av[8] = {}, ag[8] = {};
    for (int e4 = 0; e4 < 64; ++e4) {
        const int e = e4 * 4;
        float wq_[4], wk_[4], wv_[4], wg_[4];
#pragma unroll
        for (int t = 0; t < 4; ++t) {
            wq_[t] = Wq[(e + t) * 256 + tid];
            wk_[t] = Wk[(e + t) * 256 + tid];
            wv_[t] = Wv[(e + t) * 256 + tid];
            wg_[t] = Wg[(e + t) * 256 + tid];
        }
#pragma unroll
        for (int r = 0; r < 8; ++r) {
            float4 xr = *(const float4*)&xs[r][e];
            aq[r] = fmaf(xr.x, wq_[0], fmaf(xr.y, wq_[1], fmaf(xr.z, wq_[2], fmaf(xr.w, wq_[3], aq[r]))));
            ak[r] = fmaf(xr.x, wk_[0], fmaf(xr.y, wk_[1], fmaf(xr.z, wk_[2], fmaf(xr.w, wk_[3], ak[r]))));
            av[r] = fmaf(xr.x, wv_[0], fmaf(xr.y, wv_[1], fmaf(xr.z, wv_[2], fmaf(xr.w, wv_[3], av[r]))));
            ag[r] = fmaf(xr.x, wg_[0], fmaf(xr.y, wg_[1], fmaf(xr.z, wg_[2], fmaf(xr.w, wg_[3], ag[r]))));
        }
    }
    const float bgv = bg[tid];
#pragma unroll
    for (int r = 0; r < 8; ++r) {
        const size_t o = (size_t)(row0 + r) * 256 + tid;
        q[o] = aq[r] * SCALE;
        k[o] = ak[r];
        v[o] = av[r];
        g[o] = 1.f / (1.f + __expf(-(ag[r] + bgv)));
    }
}

// ---------------------------------------------------------------------------
// K2a v6 (unchanged from R9 — measured at the edge-read roofline ~96us/rep).
// Zero-LDS, DPP-reduce, all arrays constant-indexed (no address-taking ->
// no PromoteAlloca-to-LDS; that was R2..R8's hidden 16KB LDS + 14M conflicts).
// ---------------------------------------------------------------------------
#define BIAS_BODY(CUR0, CUR1, ITROW)                                          \
    {                                                                         \
        float s1 = ((CUR0.x + CUR0.y) + (CUR0.z + CUR0.w)) +                  \
                   ((CUR1.x + CUR1.y) + (CUR1.z + CUR1.w));                   \
        float s2 = fmaf(CUR0.x, CUR0.x, fmaf(CUR0.y, CUR0.y,                  \
                   fmaf(CUR0.z, CUR0.z, CUR0.w * CUR0.w)));                   \
        s2 = fmaf(CUR1.x, CUR1.x, fmaf(CUR1.y, CUR1.y,                        \
             fmaf(CUR1.z, CUR1.z, fmaf(CUR1.w, CUR1.w, s2))));                \
        float d[8];                                                           \
        _Pragma("unroll")                                                     \
        for (int hh = 0; hh < 8; ++hh) {                                      \
            float a = CUR0.x * wbf[0][hh];                                    \
            a = fmaf(CUR0.y, wbf[1][hh], a);                                  \
            a = fmaf(CUR0.z, wbf[2][hh], a);                                  \
            a = fmaf(CUR0.w, wbf[3][hh], a);                                  \
            a = fmaf(CUR1.x, wbf[4][hh], a);                                  \
            a = fmaf(CUR1.y, wbf[5][hh], a);                                  \
            a = fmaf(CUR1.z, wbf[6][hh], a);                                  \
            a = fmaf(CUR1.w, wbf[7][hh], a);                                  \
            d[hh] = a;                                                        \
        }                                                                     \
        s1 = dpp_add16(s1);                                                   \
        s2 = dpp_add16(s2);                                                   \
        _Pragma("unroll")                                                     \
        for (int hh = 0; hh < 8; ++hh) d[hh] = dpp_add16(d[hh]);              \
        const float mu = s1 * (1.f / 128.f);                                  \
        const float rstd = rsqrtf(s2 * (1.f / 128.f) - mu * mu + 1e-5f);      \
        float dh = d[0];                                                      \
        _Pragma("unroll")                                                     \
        for (int t = 1; t < 8; ++t) dh = (gl == t) ? d[t] : dh;               \
        if (gl < 8)                                                           \
            bias[(size_t)(row0 + (ITROW)) * 8 + gl] =                         \
                rstd * (dh - mu * c1l) + c0l;                                 \
    }

__global__ __launch_bounds__(256, 3) void k_bias(
    const float* __restrict__ edge, const float* __restrict__ lnw,
    const float* __restrict__ lnb, const float* __restrict__ Wb,
    float* __restrict__ bias, int reps)
{
    const int tid = threadIdx.x;
    const int wv = tid >> 6, lane = tid & 63;
    const int gl = lane & 15;
    const int rg = lane >> 4;

    float wbf[8][8];
    float c1a[8], c0a[8];
#pragma unroll
    for (int hh = 0; hh < 8; ++hh) { c1a[hh] = 0.f; c0a[hh] = 0.f; }
#pragma unroll
    for (int t = 0; t < 8; ++t) {
        const int c = (t < 4) ? (gl * 4 + t) : (64 + gl * 4 + (t - 4));
        const float w = lnw[c], bb = lnb[c];
        const float4 wa = ((const float4*)Wb)[c * 2];
        const float4 wc = ((const float4*)Wb)[c * 2 + 1];
        wbf[t][0] = w * wa.x; wbf[t][1] = w * wa.y;
        wbf[t][2] = w * wa.z; wbf[t][3] = w * wa.w;
        wbf[t][4] = w * wc.x; wbf[t][5] = w * wc.y;
        wbf[t][6] = w * wc.z; wbf[t][7] = w * wc.w;
        c0a[0] = fmaf(bb, wa.x, c0a[0]); c0a[1] = fmaf(bb, wa.y, c0a[1]);
        c0a[2] = fmaf(bb, wa.z, c0a[2]); c0a[3] = fmaf(bb, wa.w, c0a[3]);
        c0a[4] = fmaf(bb, wc.x, c0a[4]); c0a[5] = fmaf(bb, wc.y, c0a[5]);
        c0a[6] = fmaf(bb, wc.z, c0a[6]); c0a[7] = fmaf(bb, wc.w, c0a[7]);
#pragma unroll
        for (int hh = 0; hh < 8; ++hh) c1a[hh] += wbf[t][hh];
    }
#pragma unroll
    for (int hh = 0; hh < 8; ++hh) {
        c1a[hh] = dpp_add16(c1a[hh]);
        c0a[hh] = dpp_add16(c0a[hh]);
    }
    float c1l = c1a[0], c0l = c0a[0];
#pragma unroll
    for (int t = 1; t < 8; ++t) {
        const bool e = ((gl & 7) == t);
        c1l = e ? c1a[t] : c1l;
        c0l = e ? c0a[t] : c0l;
    }

    const int w = blockIdx.x * 4 + wv;     // 0..8191
    const int row0 = w * BIAS_RPW;         // 144 rows/wave
    const float4* ep = (const float4*)edge;

    for (int rep = 0; rep < reps; ++rep) {
        float4 A0, A1, B0, B1, C0, C1;
        {
            const size_t r = (size_t)(row0 + rg);
            A0 = ep[r * 32 + gl]; A1 = ep[r * 32 + 16 + gl];
        }
        {
            const size_t r = (size_t)(row0 + 4 + rg);
            B0 = ep[r * 32 + gl]; B1 = ep[r * 32 + 16 + gl];
        }

#define BSTEP(IT, CUR0, CUR1, NXT0, NXT1)                                 \
        {                                                                 \
            if ((IT) + 2 < BIAS_NT) {                                     \
                const size_t r = (size_t)(row0 + ((IT) + 2) * 4 + rg);    \
                NXT0 = ep[r * 32 + gl]; NXT1 = ep[r * 32 + 16 + gl];      \
            }                                                             \
            BIAS_BODY(CUR0, CUR1, (IT) * 4 + rg);                         \
        }

        for (int it = 0; it < BIAS_NT; it += 3) {
            BSTEP(it,     A0, A1, C0, C1);
            BSTEP(it + 1, B0, B1, A0, A1);
            BSTEP(it + 2, C0, C1, B0, B1);
        }
#undef BSTEP
    }
}

// ---------------------------------------------------------------------------
// K2b v8: flash attention, attn6's COALESCED pattern (all 64 lanes read one
// contiguous K/V row; measured 105us/rep in R9) + 2 q-rows per wave sharing
// the K/V loads (halves per-logit load cost and L2 traffic vs attn6).
// Block = 2 q-rows (2*blk, 2*blk+1 — always same batch), 4 waves each
// covering a j-quarter (48 iters x 4 j). lane = (h = lane>>3, dq = lane&7)
// owns head h dims dq*4..dq*4+3. Dot reduced over 8 lanes via pure-DPP add8.
// Merge across waves via LDS at the end (waves 0,1 finalize rows 0,1).
// ---------------------------------------------------------------------------
__global__ __launch_bounds__(256, 3) void k_attn8(
    const float* __restrict__ bias,
    const float* __restrict__ q, const float* __restrict__ k,
    const float* __restrict__ v, const float* __restrict__ g,
    float* __restrict__ res)
{
    __shared__ float mg[4][2][64][6];   // 12 KB
    const int tid = threadIdx.x;
    const int wv = tid >> 6, lane = tid & 63;
    const int bi0 = blockIdx.x * 2, bi1 = bi0 + 1;
    const int b = bi0 / NN;
    const int h = lane >> 3;

    const float4 q40 = ((const float4*)q)[(size_t)bi0 * 64 + lane];
    const float4 q41 = ((const float4*)q)[(size_t)bi1 * 64 + lane];
    const float* brow0 = bias + (size_t)bi0 * NN * 8;
    const float* brow1 = bias + (size_t)bi1 * NN * 8;
    const size_t kb = (size_t)b * NN * 64;
    const int j0 = wv * (NN / 4);     // 0,192,384,576

    float m0 = -3e38f, s0 = 0.f;
    float m1 = -3e38f, s1 = 0.f;
    float4 ac0 = make_float4(0.f, 0.f, 0.f, 0.f);
    float4 ac1 = make_float4(0.f, 0.f, 0.f, 0.f);

    for (int t = 0; t < NN / 16; ++t) {      // 48 iters x 4 j
        const int jb = j0 + t * 4;
        float l0[4], l1[4];
        float4 vc[4];
#pragma unroll
        for (int u = 0; u < 4; ++u) {
            const float4 kc = ((const float4*)k)[kb + (size_t)(jb + u) * 64 + lane];
            vc[u] = ((const float4*)v)[kb + (size_t)(jb + u) * 64 + lane];
            float d0 = fmaf(q40.x, kc.x, fmaf(q40.y, kc.y,
                       fmaf(q40.z, kc.z, q40.w * kc.w)));
            float d1 = fmaf(q41.x, kc.x, fmaf(q41.y, kc.y,
                       fmaf(q41.z, kc.z, q41.w * kc.w)));
            d0 = dpp_add8(d0);
            d1 = dpp_add8(d1);
            l0[u] = d0 + brow0[(jb + u) * 8 + h];
            l1[u] = d1 + brow1[(jb + u) * 8 + h];
        }
        // row 0
        {
            const float lm = fmaxf(fmaxf(l0[0], l0[1]), fmaxf(l0[2], l0[3]));
            const float mn = fmaxf(m0, lm);
            const float sc = __expf(m0 - mn);
            float p[4];
#pragma unroll
            for (int u = 0; u < 4; ++u) p[u] = __expf(l0[u] - mn);
            s0 = fmaf(s0, sc, (p[0] + p[1]) + (p[2] + p[3]));
            m0 = mn;
            ac0.x = fmaf(p[3], vc[3].x, fmaf(p[2], vc[2].x,
                    fmaf(p[1], vc[1].x, fmaf(p[0], vc[0].x, ac0.x * sc))));
            ac0.y = fmaf(p[3], vc[3].y, fmaf(p[2], vc[2].y,
                    fmaf(p[1], vc[1].y, fmaf(p[0], vc[0].y, ac0.y * sc))));
            ac0.z = fmaf(p[3], vc[3].z, fmaf(p[2], vc[2].z,
                    fmaf(p[1], vc[1].z, fmaf(p[0], vc[0].z, ac0.z * sc))));
            ac0.w = fmaf(p[3], vc[3].w, fmaf(p[2], vc[2].w,
                    fmaf(p[1], vc[1].w, fmaf(p[0], vc[0].w, ac0.w * sc))));
        }
        // row 1
        {
            const float lm = fmaxf(fmaxf(l1[0], l1[1]), fmaxf(l1[2], l1[3]));
            const float mn = fmaxf(m1, lm);
            const float sc = __expf(m1 - mn);
            float p[4];
#pragma unroll
            for (int u = 0; u < 4; ++u) p[u] = __expf(l1[u] - mn);
            s1 = fmaf(s1, sc, (p[0] + p[1]) + (p[2] + p[3]));
            m1 = mn;
            ac1.x = fmaf(p[3], vc[3].x, fmaf(p[2], vc[2].x,
                    fmaf(p[1], vc[1].x, fmaf(p[0], vc[0].x, ac1.x * sc))));
            ac1.y = fmaf(p[3], vc[3].y, fmaf(p[2], vc[2].y,
                    fmaf(p[1], vc[1].y, fmaf(p[0], vc[0].y, ac1.y * sc))));
            ac1.z = fmaf(p[3], vc[3].z, fmaf(p[2], vc[2].z,
                    fmaf(p[1], vc[1].z, fmaf(p[0], vc[0].z, ac1.z * sc))));
            ac1.w = fmaf(p[3], vc[3].w, fmaf(p[2], vc[2].w,
                    fmaf(p[1], vc[1].w, fmaf(p[0], vc[0].w, ac1.w * sc))));
        }
    }

    mg[wv][0][lane][0] = m0;
    mg[wv][0][lane][1] = s0;
    mg[wv][0][lane][2] = ac0.x;
    mg[wv][0][lane][3] = ac0.y;
    mg[wv][0][lane][4] = ac0.z;
    mg[wv][0][lane][5] = ac0.w;
    mg[wv][1][lane][0] = m1;
    mg[wv][1][lane][1] = s1;
    mg[wv][1][lane][2] = ac1.x;
    mg[wv][1][lane][3] = ac1.y;
    mg[wv][1][lane][4] = ac1.z;
    mg[wv][1][lane][5] = ac1.w;
    __syncthreads();

    if (wv < 2) {
        const int r = wv;               // row this wave finalizes
        const int bi = bi0 + r;
        float M = mg[0][r][lane][0];
#pragma unroll
        for (int w2 = 1; w2 < 4; ++w2) M = fmaxf(M, mg[w2][r][lane][0]);
        float S = 0.f;
        float4 A = make_float4(0.f, 0.f, 0.f, 0.f);
#pragma unroll
        for (int w2 = 0; w2 < 4; ++w2) {
            const float sc2 = __expf(mg[w2][r][lane][0] - M);
            S = fmaf(mg[w2][r][lane][1], sc2, S);
            A.x = fmaf(mg[w2][r][lane][2], sc2, A.x);
            A.y = fmaf(mg[w2][r][lane][3], sc2, A.y);
            A.z = fmaf(mg[w2][r][lane][4], sc2, A.z);
            A.w = fmaf(mg[w2][r][lane][5], sc2, A.w);
        }
        const float4 g4 = ((const float4*)g)[(size_t)bi * 64 + lane];
        const float inv = 1.f / S;
        float4 o;
        o.x = A.x * inv * g4.x;
        o.y = A.y * inv * g4.y;
        o.z = A.z * inv * g4.z;
        o.w = A.w * inv * g4.w;
        ((float4*)res)[(size_t)bi * 64 + lane] = o;
    }
}

// ---------------------------------------------------------------------------
// K3: out = res @ Wo + bo.  8 rows per block.
// ---------------------------------------------------------------------------
__global__ __launch_bounds__(256) void k_outproj(
    const float* __restrict__ res, const float* __restrict__ Wo,
    const float* __restrict__ bo, float* __restrict__ out)
{
    __shared__ float xs[8][256];
    const int tid = threadIdx.x;
    const int row0 = blockIdx.x * 8;

#pragma unroll
    for (int t = tid; t < 512; t += 256)
        ((float4*)&xs[0][0])[t] = ((const float4*)(res + (size_t)row0 * 256))[t];
    __syncthreads();

    float a[8] = {};
    for (int e4 = 0; e4 < 64; ++e4) {
        const int e = e4 * 4;
        float w_[4];
#pragma unroll
        for (int t = 0; t < 4; ++t) w_[t] = Wo[(e + t) * 256 + tid];
#pragma unroll
        for (int r = 0; r < 8; ++r) {
            float4 xr = *(const float4*)&xs[r][e];
            a[r] = fmaf(xr.x, w_[0], fmaf(xr.y, w_[1], fmaf(xr.z, w_[2], fmaf(xr.w, w_[3], a[r]))));
        }
    }
    const float bov = bo[tid];
#pragma unroll
    for (int r = 0; r < 8; ++r)
        out[(size_t)(row0 + r) * 256 + tid] = a[r] + bov;
}

// ---------------------------------------------------------------------------
extern "C" void kernel_launch(void* const* d_in, const int* in_sizes, int n_in,
                              void* d_out, int out_size, void* d_ws, size_t ws_size,
                              hipStream_t stream) {
    const float* node = (const float*)d_in[0];
    const float* edge = (const float*)d_in[1];
    const float* lnnw = (const float*)d_in[2];
    const float* lnnb = (const float*)d_in[3];
    const float* lnew = (const float*)d_in[4];
    const float* lneb = (const float*)d_in[5];
    const float* Wq   = (const float*)d_in[6];
    const float* Wk   = (const float*)d_in[7];
    const float* Wv   = (const float*)d_in[8];
    const float* Wb   = (const float*)d_in[9];
    const float* Wg   = (const float*)d_in[10];
    const float* bg   = (const float*)d_in[11];
    const float* Wo   = (const float*)d_in[12];
    const float* bo   = (const float*)d_in[13];
    float* out = (float*)d_out;

    float* ws = (float*)d_ws;
    const size_t NT = (size_t)BN * 256;
    float* q    = ws;
    float* k    = ws + NT;
    float* v    = ws + 2 * NT;
    float* g    = ws + 3 * NT;
    float* res  = ws + 4 * NT;
    float* bias = ws + 5 * NT;            // 9.44M floats = 37.75 MB

    k_lnproj<<<BN / 8, 256, 0, stream>>>(node, lnnw, lnnb, Wq, Wk, Wv, Wg, bg, q, k, v, g);
    k_bias<<<BIAS_BLOCKS, 256, 0, stream>>>(edge, lnew, lneb, Wb, bias, 1);
    k_attn8<<<BN / 2, 256, 0, stream>>>(bias, q, k, v, g, res);
    k_outproj<<<BN / 8, 256, 0, stream>>>(res, Wo, bo, out);
}